// Round 12
// baseline (169.394 us; speedup 1.0000x reference)
//
#include <hip/hip_runtime.h>
#include <cstdint>
#include <cstddef>

typedef int   v4i __attribute__((ext_vector_type(4)));
typedef float v4f __attribute__((ext_vector_type(4)));
typedef unsigned int u32;

constexpr int B_   = 64;
constexpr int CIN  = 96;
constexpr int P_   = 784;     // 28*28
constexpr int CMID = 576;
constexpr int COUT = 96;
constexpr int NOUT = B_ * COUT * P_;
constexpr float NBITF = 127.0f;
constexpr float EPSF  = 1e-5f;
constexpr float MAGICF = 12582912.0f;    // 1.5 * 2^23
constexpr int   BIASI  = 0x4B400000;     // float bits of MAGICF (low byte 0)

// x8t2: v4i X[b][pt 13][g 8][pxl 64] = k-bytes 16g..16g+15 of px pt*64+pxl
//   (g 0..5 = ic 0..95, g 6..7 = zero K-pad 96->128). One MFMA A-frag = 1 v4i.
constexpr int XB4 = 13 * 8 * 64;        // v4i per batch (6656)

__device__ __forceinline__ int dot3(u32 a, u32 w, int acc) {
#if __has_builtin(__builtin_amdgcn_sdot4)
    return __builtin_amdgcn_sdot4((int)a, (int)w, acc, false);
#else
    return acc + (int)(signed char)(a)        * (int)(signed char)(w)
               + (int)(signed char)(a >> 8)   * (int)(signed char)(w >> 8)
               + (int)(signed char)(a >> 16)  * (int)(signed char)(w >> 16);
#endif
}

__device__ __forceinline__ void tr4(u32 S0, u32 S1, u32 S2, u32 S3, u32 O[4]) {
    u32 u01 = __builtin_amdgcn_perm(S1, S0, 0x05010400u);
    u32 u23 = __builtin_amdgcn_perm(S3, S2, 0x05010400u);
    u32 v01 = __builtin_amdgcn_perm(S1, S0, 0x07030602u);
    u32 v23 = __builtin_amdgcn_perm(S3, S2, 0x07030602u);
    O[0] = __builtin_amdgcn_perm(u23, u01, 0x05040100u);
    O[1] = __builtin_amdgcn_perm(u23, u01, 0x07060302u);
    O[2] = __builtin_amdgcn_perm(v23, v01, 0x05040100u);
    O[3] = __builtin_amdgcn_perm(v23, v01, 0x07060302u);
}

__device__ __forceinline__ u32 pack4(u32 t0, u32 t1, u32 t2, u32 t3) {
    u32 p01 = __builtin_amdgcn_perm(t1, t0, 0x05010400u);
    u32 p23 = __builtin_amdgcn_perm(t3, t2, 0x05010400u);
    return __builtin_amdgcn_perm(p23, p01, 0x05040100u);
}

// ---------------------------------------------------------------------------
// prep_all: blocks [0,448) = quant_x into x8t2; blocks [448,760) = weight
// prep (4 single-wave jobs/block) emitting int8 levels + folded epilogue
// constants e1/e2/e3 = {scale, bias} per channel.
// ---------------------------------------------------------------------------
__global__ __launch_bounds__(256)
void prep_all(const float* __restrict__ x,
              const float* __restrict__ w1, const float* __restrict__ g1,
              const float* __restrict__ b1, const float* __restrict__ m1,
              const float* __restrict__ v1,
              const float* __restrict__ w2, const float* __restrict__ g2,
              const float* __restrict__ b2, const float* __restrict__ m2,
              const float* __restrict__ v2,
              const float* __restrict__ w3, const float* __restrict__ g3,
              const float* __restrict__ b3, const float* __restrict__ m3,
              const float* __restrict__ v3,
              const float* __restrict__ r0, const float* __restrict__ r1,
              const float* __restrict__ r2, const int* __restrict__ cluster,
              u32* __restrict__ x8t2,
              int8_t* __restrict__ w1qp, float2* __restrict__ e1,
              v4i* __restrict__ w2pk,    float2* __restrict__ e2,
              int8_t* __restrict__ w3qp, float2* __restrict__ e3)
{
    __shared__ u32 T[112 * 37];
    int tid = threadIdx.x;
    int c = cluster[0];

    if (blockIdx.x < 448) {
        int pt0 = blockIdx.x % 7, b = blockIdx.x / 7;
        float inv_s0 = NBITF / r0[c];

        for (int i = tid; i < 112 * 8; i += 256) {      // zero kdw 24..31
            int row = i >> 3, cc = 24 + (i & 7);
            T[row * 37 + cc] = 0u;
        }
        for (int u = tid; u < 24 * 28; u += 256) {
            int pq = u % 28, icq = u / 28;
            int pxb = pt0 * 112 + pq * 4;
            int q[4][4];
            #pragma unroll
            for (int j = 0; j < 4; j++) {
                v4f xv = *(const v4f*)(x + ((size_t)b * CIN + icq * 4 + j) * P_ + pxb);
                #pragma unroll
                for (int i = 0; i < 4; i++)
                    q[j][i] = (int)fminf(fmaxf(rintf(xv[i] * inv_s0), -127.f), 127.f);
            }
            #pragma unroll
            for (int i = 0; i < 4; i++) {
                u32 t0 = __builtin_amdgcn_perm((u32)q[1][i], (u32)q[0][i], 0x00000400u);
                u32 t1 = __builtin_amdgcn_perm((u32)q[3][i], (u32)q[2][i], 0x00000400u);
                T[(pq * 4 + i) * 37 + icq] = __builtin_amdgcn_perm(t1, t0, 0x05040100u);
            }
        }
        __syncthreads();
        u32* gb = x8t2 + (size_t)b * XB4 * 4;
        for (int i = tid; i < 32 * 112; i += 256) {
            int icq = i / 112, pxo = i - icq * 112;
            int px = pt0 * 112 + pxo;
            gb[(((px >> 6) * 8 + (icq >> 2)) * 64 + (px & 63)) * 4 + (icq & 3)] =
                T[pxo * 37 + icq];
        }
        return;
    }

    int lane = tid & 63, wv = tid >> 6;
    int blk = (blockIdx.x - 448) * 4 + wv;   // 0..1247

    const float *w, *g, *bb, *mm, *vv;
    int oc, K, which;
    if (blk < CMID)            { which = 0; w = w1; g = g1; bb = b1; mm = m1; vv = v1; oc = blk;            K = CIN;  }
    else if (blk < 2 * CMID)   { which = 1; w = w2; g = g2; bb = b2; mm = m2; vv = v2; oc = blk - CMID;     K = 9;    }
    else                       { which = 2; w = w3; g = g3; bb = b3; mm = m3; vv = v3; oc = blk - 2 * CMID; K = CMID; }

    float scale = g[oc] / sqrtf(vv[oc] + EPSF);

    float mx = 0.f;
    for (int k = lane; k < K; k += 64)
        mx = fmaxf(mx, fabsf(w[oc * K + k] * scale));
    #pragma unroll
    for (int off = 1; off < 64; off <<= 1)
        mx = fmaxf(mx, __shfl_xor(mx, off));

    float s = mx / NBITF;

    int myq = 0;
    for (int k = lane; k < K; k += 64) {
        float wf = w[oc * K + k] * scale;
        float q  = fminf(fmaxf(rintf(wf / s), -127.f), 127.f);
        if (which == 0)      w1qp[oc * 144 + k] = (int8_t)q;
        else if (which == 1) myq = (int)q;
        else                 w3qp[oc * 592 + k] = (int8_t)q;
    }
    if (which == 0 && lane < 12)
        ((u32*)(w1qp + oc * 144))[24 + lane] = 0u;
    if (which == 1) {
        u32 qq[9];
        #pragma unroll
        for (int t = 0; t < 9; t++) qq[t] = (u32)__shfl(myq, t, 64) & 0xffu;
        if (lane == 0) {
            v4i pk;
            pk[0] = (int)(qq[0] | (qq[1] << 8) | (qq[2] << 16));
            pk[1] = (int)(qq[3] | (qq[4] << 8) | (qq[5] << 16));
            pk[2] = (int)(qq[6] | (qq[7] << 8) | (qq[8] << 16));
            pk[3] = 0;
            w2pk[oc] = pk;
        }
    }
    if (lane == 0) {
        float bf = bb[oc] - mm[oc] * scale;
        float s0 = r0[c] / NBITF, s1 = r1[c] / NBITF, s2 = r2[c] / NBITF;
        if (which == 0) {
            float inv_s1 = NBITF / r1[c];
            e1[oc] = make_float2(s0 * s * inv_s1, bf * inv_s1);
        } else if (which == 1) {
            float inv_s2 = NBITF / r2[c];
            e2[oc] = make_float2(s1 * s * inv_s2, bf * inv_s2);
        } else {
            e3[oc] = make_float2(s2 * s, bf);
        }
    }
}

// ---------------------------------------------------------------------------
// conv123b: fully fused conv1 + depthwise + conv3, occupancy-tuned.
// Block = all 576 ch x 2 out rows; wave owns 144 ch in NINE chunks of 16
// through small per-wave scratch (wave-ordered DS, no intra-phase barriers).
// A-frags read directly from global x8t2 (L1-resident after chunk 1; no xs
// staging, no first barrier). tr4 deposits ch-packed v4i into shared
// y2c[36kg][57]; one block barrier; conv3 MFMA + residual + requant.
// Grid (14 rt, 64 b); LDS 44.1 KB -> 3 blocks/CU.
// ---------------------------------------------------------------------------
__global__ __launch_bounds__(256)
void conv123b(const v4i* __restrict__ x8t2, const v4i* __restrict__ w1q4,
              const float2* __restrict__ e1,
              const v4i* __restrict__ w2pk, const float2* __restrict__ e2,
              const int8_t* __restrict__ w3qp, const float2* __restrict__ e3,
              const float* __restrict__ x,
              const float* __restrict__ r1, const float* __restrict__ r2,
              const float* __restrict__ r3, const int* __restrict__ cluster,
              float* __restrict__ out)
{
    __shared__ u32 y1s[4][16 * 29];     // per-wave scratch    7424 B
    __shared__ u32 y2s[4][16 * 15];     // per-wave scratch    3840 B
    __shared__ v4i y2c[36 * 57];        // shared ch-packed   32832 B

    int tid = threadIdx.x, b = blockIdx.y, rt = blockIdx.x;
    int R0 = 2 * rt;
    int W0 = (R0 - 1) * 28;             // window px base (may be -28)
    int lane = tid & 63, wv = tid >> 6;
    int n = lane & 15, q4 = lane >> 4;

    int   c      = cluster[0];
    int   u1i    = (int)fminf(rintf(6.f * NBITF / r1[c]), 127.f);
    int   u2i    = (int)fminf(rintf(6.f * NBITF / r2[c]), 127.f);
    float s3     = r3[c] / NBITF;
    float inv_s3 = NBITF / r3[c];

    // window A-frag base offsets (reused across all 9 chunks; L1-resident)
    const v4i* xb = x8t2 + (size_t)b * XB4;
    int pb[7];
    #pragma unroll
    for (int jm = 0; jm < 7; jm++) {
        int px = min(max(W0 + 16 * jm + n, 0), P_ - 1);
        pb[jm] = (px >> 6) * 512 + (px & 63);
    }

    u32* myY1 = y1s[wv];
    u32* myY2 = y2s[wv];

    for (int ck = 0; ck < 9; ck++) {
        int oc0 = wv * 144 + ck * 16;

        // ---- conv1: 16 oc, jm-outer, fused epilogue ----
        int    oc  = oc0 + n;
        v4i    bw0 = w1q4[oc * 9 + q4];
        v4i    bw1 = w1q4[oc * 9 + 4 + q4];
        float2 ee  = e1[oc];

        #pragma unroll
        for (int jm = 0; jm < 7; jm++) {
            v4i af0 = xb[pb[jm] + q4 * 64];
            v4i af1 = xb[pb[jm] + (4 + q4) * 64];
            int dw = 4 * jm + q4;                       // 0..27
            bool valid = (unsigned)(W0 + 4 * dw) < (unsigned)P_;

            v4i acc = (v4i){0, 0, 0, 0};
            acc = __builtin_amdgcn_mfma_i32_16x16x64_i8(af0, bw0, acc, 0, 0, 0);
            acc = __builtin_amdgcn_mfma_i32_16x16x64_i8(af1, bw1, acc, 0, 0, 0);

            u32 t[4];
            #pragma unroll
            for (int r = 0; r < 4; r++) {
                float f = fmaf((float)acc[r], ee.x, ee.y) + MAGICF;
                t[r] = (u32)min(max(__float_as_int(f), BIASI), BIASI + u1i);
            }
            u32 pk = pack4(t[0], t[1], t[2], t[3]);
            myY1[n * 29 + dw] = valid ? pk : 0u;
        }

        // ---- depthwise 3x3: 16 ch x 2 rows = 32 units on lanes 0..31 ----
        if (lane < 32) {
            int chl = lane >> 1, orow = lane & 1;
            int ch  = oc0 + chl;
            int rb  = chl * 29 + orow * 7;

            v4i wpk = w2pk[ch];
            u32 pk0 = (u32)wpk[0], pk1 = (u32)wpk[1], pk2 = (u32)wpk[2];
            float2 e = e2[ch];

            u32 M0 = 0, M1 = 0, M2 = 0;
            u32 D0 = myY1[rb], D1 = myY1[rb + 7], D2 = myY1[rb + 14];
            #pragma unroll
            for (int xq = 0; xq < 7; xq++) {
                u32 N0, N1, N2;
                if (xq < 6) {
                    N0 = myY1[rb + xq + 1];
                    N1 = myY1[rb + 7 + xq + 1];
                    N2 = myY1[rb + 14 + xq + 1];
                } else { N0 = N1 = N2 = 0u; }

                int a0, a1, a2, a3;
                a0 = dot3(__builtin_amdgcn_alignbyte(D0, M0, 3), pk0, 0);
                a0 = dot3(__builtin_amdgcn_alignbyte(D1, M1, 3), pk1, a0);
                a0 = dot3(__builtin_amdgcn_alignbyte(D2, M2, 3), pk2, a0);
                a1 = dot3(D0, pk0, 0);
                a1 = dot3(D1, pk1, a1);
                a1 = dot3(D2, pk2, a1);
                a2 = dot3(__builtin_amdgcn_alignbyte(N0, D0, 1), pk0, 0);
                a2 = dot3(__builtin_amdgcn_alignbyte(N1, D1, 1), pk1, a2);
                a2 = dot3(__builtin_amdgcn_alignbyte(N2, D2, 1), pk2, a2);
                a3 = dot3(__builtin_amdgcn_alignbyte(N0, D0, 2), pk0, 0);
                a3 = dot3(__builtin_amdgcn_alignbyte(N1, D1, 2), pk1, a3);
                a3 = dot3(__builtin_amdgcn_alignbyte(N2, D2, 2), pk2, a3);

                int aa[4] = {a0, a1, a2, a3};
                u32 tq[4];
                #pragma unroll
                for (int i = 0; i < 4; i++) {
                    float f = fmaf((float)aa[i], e.x, e.y) + MAGICF;
                    tq[i] = (u32)min(max(__float_as_int(f), BIASI), BIASI + u2i);
                }
                myY2[chl * 15 + orow * 7 + xq] = pack4(tq[0], tq[1], tq[2], tq[3]);

                M0 = D0; M1 = D1; M2 = D2;
                D0 = N0; D1 = N1; D2 = N2;
            }
        }

        // ---- tr4 -> shared ch-packed y2c (this chunk = 1 kg; lanes 0..13) --
        if (lane < 14) {
            int d = lane;
            u32 O[4][4];
            #pragma unroll
            for (int j = 0; j < 4; j++) {
                int cb = (4 * j) * 15 + d;
                tr4(myY2[cb], myY2[cb + 15], myY2[cb + 30], myY2[cb + 45], O[j]);
            }
            int kgG = wv * 9 + ck;                      // 0..35
            #pragma unroll
            for (int i = 0; i < 4; i++)
                y2c[kgG * 57 + 4 * d + i] =
                    (v4i){(int)O[0][i], (int)O[1][i], (int)O[2][i], (int)O[3][i]};
        }
    }
    __syncthreads();   // y2c complete

    // ---- conv3 MFMA + residual + requant ----
    int pxl = wv * 16 + n;               // 0..63, valid < 56
    int pxc = min(pxl, 55);
    const v4i* w34 = (const v4i*)w3qp;   // 37 v4i per oc row

    v4i acc3[6];
    #pragma unroll
    for (int i = 0; i < 6; i++) acc3[i] = (v4i){0, 0, 0, 0};

    #pragma unroll
    for (int ks = 0; ks < 9; ks++) {
        v4i bfr = y2c[(4 * ks + q4) * 57 + pxc];
        #pragma unroll
        for (int i = 0; i < 6; i++) {
            v4i afr = w34[(i * 16 + n) * 37 + 4 * ks + q4];
            acc3[i] = __builtin_amdgcn_mfma_i32_16x16x64_i8(afr, bfr, acc3[i], 0, 0, 0);
        }
    }

    if (pxl < 56) {
        int px = R0 * 28 + pxl;
        #pragma unroll
        for (int i = 0; i < 6; i++) {
            #pragma unroll
            for (int r = 0; r < 4; r++) {
                int    oc = i * 16 + q4 * 4 + r;
                float2 e  = e3[oc];
                size_t gi = (size_t)(b * COUT + oc) * P_ + px;
                float v  = fmaf((float)acc3[i][r], e.x, e.y) + x[gi];
                float f  = fmaf(v, inv_s3, MAGICF);
                int lvl  = min(max(__float_as_int(f) - BIASI, -127), 127);
                out[gi]  = (float)lvl * s3;
            }
        }
    }
    if (rt == 0 && b == 0 && tid == 0)
        out[NOUT] = s3;
}

// ---------------------------------------------------------------------------
extern "C" void kernel_launch(void* const* d_in, const int* in_sizes, int n_in,
                              void* d_out, int out_size, void* d_ws, size_t ws_size,
                              hipStream_t stream)
{
    const float* x  = (const float*)d_in[0];
    const float* w1 = (const float*)d_in[1];
    const float* g1 = (const float*)d_in[2];
    const float* b1 = (const float*)d_in[3];
    const float* m1 = (const float*)d_in[4];
    const float* v1 = (const float*)d_in[5];
    const float* w2 = (const float*)d_in[6];
    const float* g2 = (const float*)d_in[7];
    const float* b2 = (const float*)d_in[8];
    const float* m2 = (const float*)d_in[9];
    const float* v2 = (const float*)d_in[10];
    const float* w3 = (const float*)d_in[11];
    const float* g3 = (const float*)d_in[12];
    const float* b3 = (const float*)d_in[13];
    const float* m3 = (const float*)d_in[14];
    const float* v3 = (const float*)d_in[15];
    const float* r0 = (const float*)d_in[16];
    const float* r1 = (const float*)d_in[17];
    const float* r2 = (const float*)d_in[18];
    const float* r3 = (const float*)d_in[19];
    const int*   cl = (const int*)d_in[20];

    float* out = (float*)d_out;

    char*  ws  = (char*)d_ws;
    size_t off = 0;
    auto carve = [&](size_t bytes) {
        size_t cur = off;
        off = (off + bytes + 255) & ~(size_t)255;
        return (void*)(ws + cur);
    };
    int8_t* w1qp = (int8_t*)carve((size_t)CMID * 144);
    float2* e1   = (float2*)carve((size_t)CMID * 8);
    v4i*    w2pk = (v4i*)carve((size_t)CMID * 16);
    float2* e2   = (float2*)carve((size_t)CMID * 8);
    int8_t* w3qp = (int8_t*)carve((size_t)COUT * 592);
    float2* e3   = (float2*)carve((size_t)COUT * 8);
    u32*    x8t2 = (u32*)carve((size_t)B_ * XB4 * 16);   // 6.8 MB
    (void)ws_size; (void)in_sizes; (void)n_in; (void)out_size;

    prep_all<<<dim3(760), dim3(256), 0, stream>>>(
        x, w1, g1, b1, m1, v1, w2, g2, b2, m2, v2, w3, g3, b3, m3, v3,
        r0, r1, r2, cl, x8t2,
        w1qp, e1, w2pk, e2, w3qp, e3);

    conv123b<<<dim3(14, B_), dim3(256), 0, stream>>>(
        (const v4i*)x8t2, (const v4i*)w1qp, e1, w2pk, e2, w3qp, e3,
        x, r1, r2, r3, cl, out);
}

// Round 13
// 164.221 us; speedup vs baseline: 1.0315x; 1.0315x over previous
//
#include <hip/hip_runtime.h>
#include <cstdint>
#include <cstddef>

typedef int   v4i __attribute__((ext_vector_type(4)));
typedef float v4f __attribute__((ext_vector_type(4)));
typedef unsigned int u32;

constexpr int B_   = 64;
constexpr int CIN  = 96;
constexpr int P_   = 784;     // 28*28
constexpr int CMID = 576;
constexpr int COUT = 96;
constexpr int NOUT = B_ * COUT * P_;
constexpr float NBITF = 127.0f;
constexpr float EPSF  = 1e-5f;
constexpr float MAGICF = 12582912.0f;    // 1.5 * 2^23
constexpr int   BIASI  = 0x4B400000;     // float bits of MAGICF (low byte 0)

// x8t2: v4i X[b][pt 13][g 8][pxl 64] = k-bytes 16g..16g+15 of px pt*64+pxl
//   (g 0..5 = ic 0..95, g 6..7 = zero K-pad 96->128). One MFMA A-frag = 1 v4i.
constexpr int XB4 = 13 * 8 * 64;        // v4i per batch (6656)

__device__ __forceinline__ int dot3(u32 a, u32 w, int acc) {
#if __has_builtin(__builtin_amdgcn_sdot4)
    return __builtin_amdgcn_sdot4((int)a, (int)w, acc, false);
#else
    return acc + (int)(signed char)(a)        * (int)(signed char)(w)
               + (int)(signed char)(a >> 8)   * (int)(signed char)(w >> 8)
               + (int)(signed char)(a >> 16)  * (int)(signed char)(w >> 16);
#endif
}

__device__ __forceinline__ void tr4(u32 S0, u32 S1, u32 S2, u32 S3, u32 O[4]) {
    u32 u01 = __builtin_amdgcn_perm(S1, S0, 0x05010400u);
    u32 u23 = __builtin_amdgcn_perm(S3, S2, 0x05010400u);
    u32 v01 = __builtin_amdgcn_perm(S1, S0, 0x07030602u);
    u32 v23 = __builtin_amdgcn_perm(S3, S2, 0x07030602u);
    O[0] = __builtin_amdgcn_perm(u23, u01, 0x05040100u);
    O[1] = __builtin_amdgcn_perm(u23, u01, 0x07060302u);
    O[2] = __builtin_amdgcn_perm(v23, v01, 0x05040100u);
    O[3] = __builtin_amdgcn_perm(v23, v01, 0x07060302u);
}

__device__ __forceinline__ u32 pack4(u32 t0, u32 t1, u32 t2, u32 t3) {
    u32 p01 = __builtin_amdgcn_perm(t1, t0, 0x05010400u);
    u32 p23 = __builtin_amdgcn_perm(t3, t2, 0x05010400u);
    return __builtin_amdgcn_perm(p23, p01, 0x05040100u);
}

// ---------------------------------------------------------------------------
// prep_all: blocks [0,448) = quant_x into x8t2; blocks [448,760) = weight
// prep (4 single-wave jobs/block) emitting int8 levels + folded epilogue
// constants e1/e2/e3 = {scale, bias} per channel.
// ---------------------------------------------------------------------------
__global__ __launch_bounds__(256)
void prep_all(const float* __restrict__ x,
              const float* __restrict__ w1, const float* __restrict__ g1,
              const float* __restrict__ b1, const float* __restrict__ m1,
              const float* __restrict__ v1,
              const float* __restrict__ w2, const float* __restrict__ g2,
              const float* __restrict__ b2, const float* __restrict__ m2,
              const float* __restrict__ v2,
              const float* __restrict__ w3, const float* __restrict__ g3,
              const float* __restrict__ b3, const float* __restrict__ m3,
              const float* __restrict__ v3,
              const float* __restrict__ r0, const float* __restrict__ r1,
              const float* __restrict__ r2, const int* __restrict__ cluster,
              u32* __restrict__ x8t2,
              int8_t* __restrict__ w1qp, float2* __restrict__ e1,
              v4i* __restrict__ w2pk,    float2* __restrict__ e2,
              int8_t* __restrict__ w3qp, float2* __restrict__ e3)
{
    __shared__ u32 T[112 * 37];
    int tid = threadIdx.x;
    int c = cluster[0];

    if (blockIdx.x < 448) {
        int pt0 = blockIdx.x % 7, b = blockIdx.x / 7;
        float inv_s0 = NBITF / r0[c];

        for (int i = tid; i < 112 * 8; i += 256) {      // zero kdw 24..31
            int row = i >> 3, cc = 24 + (i & 7);
            T[row * 37 + cc] = 0u;
        }
        for (int u = tid; u < 24 * 28; u += 256) {
            int pq = u % 28, icq = u / 28;
            int pxb = pt0 * 112 + pq * 4;
            int q[4][4];
            #pragma unroll
            for (int j = 0; j < 4; j++) {
                v4f xv = *(const v4f*)(x + ((size_t)b * CIN + icq * 4 + j) * P_ + pxb);
                #pragma unroll
                for (int i = 0; i < 4; i++)
                    q[j][i] = (int)fminf(fmaxf(rintf(xv[i] * inv_s0), -127.f), 127.f);
            }
            #pragma unroll
            for (int i = 0; i < 4; i++) {
                u32 t0 = __builtin_amdgcn_perm((u32)q[1][i], (u32)q[0][i], 0x00000400u);
                u32 t1 = __builtin_amdgcn_perm((u32)q[3][i], (u32)q[2][i], 0x00000400u);
                T[(pq * 4 + i) * 37 + icq] = __builtin_amdgcn_perm(t1, t0, 0x05040100u);
            }
        }
        __syncthreads();
        u32* gb = x8t2 + (size_t)b * XB4 * 4;
        for (int i = tid; i < 32 * 112; i += 256) {
            int icq = i / 112, pxo = i - icq * 112;
            int px = pt0 * 112 + pxo;
            gb[(((px >> 6) * 8 + (icq >> 2)) * 64 + (px & 63)) * 4 + (icq & 3)] =
                T[pxo * 37 + icq];
        }
        return;
    }

    int lane = tid & 63, wv = tid >> 6;
    int blk = (blockIdx.x - 448) * 4 + wv;   // 0..1247

    const float *w, *g, *bb, *mm, *vv;
    int oc, K, which;
    if (blk < CMID)            { which = 0; w = w1; g = g1; bb = b1; mm = m1; vv = v1; oc = blk;            K = CIN;  }
    else if (blk < 2 * CMID)   { which = 1; w = w2; g = g2; bb = b2; mm = m2; vv = v2; oc = blk - CMID;     K = 9;    }
    else                       { which = 2; w = w3; g = g3; bb = b3; mm = m3; vv = v3; oc = blk - 2 * CMID; K = CMID; }

    float scale = g[oc] / sqrtf(vv[oc] + EPSF);

    float mx = 0.f;
    for (int k = lane; k < K; k += 64)
        mx = fmaxf(mx, fabsf(w[oc * K + k] * scale));
    #pragma unroll
    for (int off = 1; off < 64; off <<= 1)
        mx = fmaxf(mx, __shfl_xor(mx, off));

    float s = mx / NBITF;

    int myq = 0;
    for (int k = lane; k < K; k += 64) {
        float wf = w[oc * K + k] * scale;
        float q  = fminf(fmaxf(rintf(wf / s), -127.f), 127.f);
        if (which == 0)      w1qp[oc * 144 + k] = (int8_t)q;
        else if (which == 1) myq = (int)q;
        else                 w3qp[oc * 592 + k] = (int8_t)q;
    }
    if (which == 0 && lane < 12)
        ((u32*)(w1qp + oc * 144))[24 + lane] = 0u;
    if (which == 1) {
        u32 qq[9];
        #pragma unroll
        for (int t = 0; t < 9; t++) qq[t] = (u32)__shfl(myq, t, 64) & 0xffu;
        if (lane == 0) {
            v4i pk;
            pk[0] = (int)(qq[0] | (qq[1] << 8) | (qq[2] << 16));
            pk[1] = (int)(qq[3] | (qq[4] << 8) | (qq[5] << 16));
            pk[2] = (int)(qq[6] | (qq[7] << 8) | (qq[8] << 16));
            pk[3] = 0;
            w2pk[oc] = pk;
        }
    }
    if (lane == 0) {
        float bf = bb[oc] - mm[oc] * scale;
        float s0 = r0[c] / NBITF, s1 = r1[c] / NBITF, s2 = r2[c] / NBITF;
        if (which == 0) {
            float inv_s1 = NBITF / r1[c];
            e1[oc] = make_float2(s0 * s * inv_s1, bf * inv_s1);
        } else if (which == 1) {
            float inv_s2 = NBITF / r2[c];
            e2[oc] = make_float2(s1 * s * inv_s2, bf * inv_s2);
        } else {
            e3[oc] = make_float2(s2 * s, bf);
        }
    }
}

// ---------------------------------------------------------------------------
// conv123c: fully fused conv1 + depthwise + conv3. Block = all 576 ch x 2
// out rows; wave owns 144 ch in THREE chunks of 48 (R11's lane utilization)
// through per-wave y1 scratch (wave-ordered DS, no intra-phase barriers).
// A-frags direct from global x8t2 (L1-resident; no xs staging). Depthwise
// writes y2 IN-PLACE over y1 rows 0/3 (each y1 dword is consumed exactly
// once by the sliding-register loop before its slot is overwritten), so the
// separate y2 scratch is gone: LDS = 22.3 (y1) + 32.3 (y2c) = 54.5 KB ->
// 3 blocks/CU. One block barrier; conv3 MFMA + residual + requant.
// Grid (14 rt, 64 b).
// ---------------------------------------------------------------------------
__global__ __launch_bounds__(256)
void conv123c(const v4i* __restrict__ x8t2, const v4i* __restrict__ w1q4,
              const float2* __restrict__ e1,
              const v4i* __restrict__ w2pk, const float2* __restrict__ e2,
              const int8_t* __restrict__ w3qp, const float2* __restrict__ e3,
              const float* __restrict__ x,
              const float* __restrict__ r1, const float* __restrict__ r2,
              const float* __restrict__ r3, const int* __restrict__ cluster,
              float* __restrict__ out)
{
    __shared__ u32 y1s[4][48 * 29];     // per-wave scratch   22272 B
    __shared__ v4i y2c[36 * 56];        // shared ch-packed   32256 B

    int tid = threadIdx.x, b = blockIdx.y, rt = blockIdx.x;
    int R0 = 2 * rt;
    int W0 = (R0 - 1) * 28;             // window px base (may be -28)
    int lane = tid & 63, wv = tid >> 6;
    int n = lane & 15, q4 = lane >> 4;

    int   c      = cluster[0];
    int   u1i    = (int)fminf(rintf(6.f * NBITF / r1[c]), 127.f);
    int   u2i    = (int)fminf(rintf(6.f * NBITF / r2[c]), 127.f);
    float s3     = r3[c] / NBITF;
    float inv_s3 = NBITF / r3[c];

    // window A-frag base offsets (reused across chunks; L1-resident)
    const v4i* xb = x8t2 + (size_t)b * XB4;
    int pb[7];
    #pragma unroll
    for (int jm = 0; jm < 7; jm++) {
        int px = min(max(W0 + 16 * jm + n, 0), P_ - 1);
        pb[jm] = (px >> 6) * 512 + (px & 63);
    }

    u32* myY1 = y1s[wv];

    for (int ck = 0; ck < 3; ck++) {
        int oc0 = wv * 144 + ck * 48;

        // ---- conv1: 48 oc, jm-outer with jn inner, fused epilogue ----
        v4i    bw[3][2];
        float2 ee[3];
        #pragma unroll
        for (int jn = 0; jn < 3; jn++) {
            int oc = oc0 + 16 * jn + n;
            bw[jn][0] = w1q4[oc * 9 + q4];
            bw[jn][1] = w1q4[oc * 9 + 4 + q4];
            ee[jn] = e1[oc];
        }
        #pragma unroll
        for (int jm = 0; jm < 7; jm++) {
            v4i af0 = xb[pb[jm] + q4 * 64];
            v4i af1 = xb[pb[jm] + (4 + q4) * 64];
            int dw = 4 * jm + q4;                       // 0..27
            bool valid = (unsigned)(W0 + 4 * dw) < (unsigned)P_;

            #pragma unroll
            for (int jn = 0; jn < 3; jn++) {
                v4i acc = (v4i){0, 0, 0, 0};
                acc = __builtin_amdgcn_mfma_i32_16x16x64_i8(af0, bw[jn][0], acc, 0, 0, 0);
                acc = __builtin_amdgcn_mfma_i32_16x16x64_i8(af1, bw[jn][1], acc, 0, 0, 0);
                u32 t[4];
                #pragma unroll
                for (int r = 0; r < 4; r++) {
                    float f = fmaf((float)acc[r], ee[jn].x, ee[jn].y) + MAGICF;
                    t[r] = (u32)min(max(__float_as_int(f), BIASI), BIASI + u1i);
                }
                u32 pk = pack4(t[0], t[1], t[2], t[3]);
                myY1[(16 * jn + n) * 29 + dw] = valid ? pk : 0u;
            }
        }

        // ---- depthwise 3x3: 48 ch x 2 rows = 96 units over 64 lanes.
        //      y2 written IN-PLACE: orow0 -> y1 row0 slot, orow1 -> row3.
        for (int u = lane; u < 96; u += 64) {
            int chl = u >> 1, orow = u & 1;
            int ch  = oc0 + chl;
            int rb  = chl * 29 + orow * 7;              // first read row
            int wb  = chl * 29 + orow * 21;             // write row (0 or 3)

            v4i wpk = w2pk[ch];
            u32 pk0 = (u32)wpk[0], pk1 = (u32)wpk[1], pk2 = (u32)wpk[2];
            float2 e = e2[ch];

            u32 M0 = 0, M1 = 0, M2 = 0;
            u32 D0 = myY1[rb], D1 = myY1[rb + 7], D2 = myY1[rb + 14];
            #pragma unroll
            for (int xq = 0; xq < 7; xq++) {
                u32 N0, N1, N2;
                if (xq < 6) {
                    N0 = myY1[rb + xq + 1];
                    N1 = myY1[rb + 7 + xq + 1];
                    N2 = myY1[rb + 14 + xq + 1];
                } else { N0 = N1 = N2 = 0u; }

                int a0, a1, a2, a3;
                a0 = dot3(__builtin_amdgcn_alignbyte(D0, M0, 3), pk0, 0);
                a0 = dot3(__builtin_amdgcn_alignbyte(D1, M1, 3), pk1, a0);
                a0 = dot3(__builtin_amdgcn_alignbyte(D2, M2, 3), pk2, a0);
                a1 = dot3(D0, pk0, 0);
                a1 = dot3(D1, pk1, a1);
                a1 = dot3(D2, pk2, a1);
                a2 = dot3(__builtin_amdgcn_alignbyte(N0, D0, 1), pk0, 0);
                a2 = dot3(__builtin_amdgcn_alignbyte(N1, D1, 1), pk1, a2);
                a2 = dot3(__builtin_amdgcn_alignbyte(N2, D2, 1), pk2, a2);
                a3 = dot3(__builtin_amdgcn_alignbyte(N0, D0, 2), pk0, 0);
                a3 = dot3(__builtin_amdgcn_alignbyte(N1, D1, 2), pk1, a3);
                a3 = dot3(__builtin_amdgcn_alignbyte(N2, D2, 2), pk2, a3);

                int aa[4] = {a0, a1, a2, a3};
                u32 tq[4];
                #pragma unroll
                for (int i = 0; i < 4; i++) {
                    float f = fmaf((float)aa[i], e.x, e.y) + MAGICF;
                    tq[i] = (u32)min(max(__float_as_int(f), BIASI), BIASI + u2i);
                }
                myY1[wb + xq] = pack4(tq[0], tq[1], tq[2], tq[3]);

                M0 = D0; M1 = D1; M2 = D2;
                D0 = N0; D1 = N1; D2 = N2;
            }
        }

        // ---- tr4 -> shared ch-packed y2c (42 units, lanes 0..41) ----
        if (lane < 42) {
            int kgl = lane / 14, d = lane - kgl * 14;   // kgl 0..2, d 0..13
            int off = d + ((d >= 7) ? 14 : 0);          // y2 slot within ch
            u32 O[4][4];
            #pragma unroll
            for (int j = 0; j < 4; j++) {
                int ch0 = 16 * kgl + 4 * j;
                tr4(myY1[(ch0 + 0) * 29 + off], myY1[(ch0 + 1) * 29 + off],
                    myY1[(ch0 + 2) * 29 + off], myY1[(ch0 + 3) * 29 + off], O[j]);
            }
            int kgG = wv * 9 + ck * 3 + kgl;            // 0..35
            #pragma unroll
            for (int i = 0; i < 4; i++)
                y2c[kgG * 56 + 4 * d + i] =
                    (v4i){(int)O[0][i], (int)O[1][i], (int)O[2][i], (int)O[3][i]};
        }
    }
    __syncthreads();   // y2c complete

    // ---- conv3 MFMA + residual + requant ----
    int pxl = wv * 16 + n;               // 0..63, valid < 56
    int pxc = min(pxl, 55);
    const v4i* w34 = (const v4i*)w3qp;   // 37 v4i per oc row

    v4i acc3[6];
    #pragma unroll
    for (int i = 0; i < 6; i++) acc3[i] = (v4i){0, 0, 0, 0};

    #pragma unroll
    for (int ks = 0; ks < 9; ks++) {
        v4i bfr = y2c[(4 * ks + q4) * 56 + pxc];
        #pragma unroll
        for (int i = 0; i < 6; i++) {
            v4i afr = w34[(i * 16 + n) * 37 + 4 * ks + q4];
            acc3[i] = __builtin_amdgcn_mfma_i32_16x16x64_i8(afr, bfr, acc3[i], 0, 0, 0);
        }
    }

    if (pxl < 56) {
        int px = R0 * 28 + pxl;
        #pragma unroll
        for (int i = 0; i < 6; i++) {
            #pragma unroll
            for (int r = 0; r < 4; r++) {
                int    oc = i * 16 + q4 * 4 + r;
                float2 e  = e3[oc];
                size_t gi = (size_t)(b * COUT + oc) * P_ + px;
                float v  = fmaf((float)acc3[i][r], e.x, e.y) + x[gi];
                float f  = fmaf(v, inv_s3, MAGICF);
                int lvl  = min(max(__float_as_int(f) - BIASI, -127), 127);
                out[gi]  = (float)lvl * s3;
            }
        }
    }
    if (rt == 0 && b == 0 && tid == 0)
        out[NOUT] = s3;
}

// ---------------------------------------------------------------------------
extern "C" void kernel_launch(void* const* d_in, const int* in_sizes, int n_in,
                              void* d_out, int out_size, void* d_ws, size_t ws_size,
                              hipStream_t stream)
{
    const float* x  = (const float*)d_in[0];
    const float* w1 = (const float*)d_in[1];
    const float* g1 = (const float*)d_in[2];
    const float* b1 = (const float*)d_in[3];
    const float* m1 = (const float*)d_in[4];
    const float* v1 = (const float*)d_in[5];
    const float* w2 = (const float*)d_in[6];
    const float* g2 = (const float*)d_in[7];
    const float* b2 = (const float*)d_in[8];
    const float* m2 = (const float*)d_in[9];
    const float* v2 = (const float*)d_in[10];
    const float* w3 = (const float*)d_in[11];
    const float* g3 = (const float*)d_in[12];
    const float* b3 = (const float*)d_in[13];
    const float* m3 = (const float*)d_in[14];
    const float* v3 = (const float*)d_in[15];
    const float* r0 = (const float*)d_in[16];
    const float* r1 = (const float*)d_in[17];
    const float* r2 = (const float*)d_in[18];
    const float* r3 = (const float*)d_in[19];
    const int*   cl = (const int*)d_in[20];

    float* out = (float*)d_out;

    char*  ws  = (char*)d_ws;
    size_t off = 0;
    auto carve = [&](size_t bytes) {
        size_t cur = off;
        off = (off + bytes + 255) & ~(size_t)255;
        return (void*)(ws + cur);
    };
    int8_t* w1qp = (int8_t*)carve((size_t)CMID * 144);
    float2* e1   = (float2*)carve((size_t)CMID * 8);
    v4i*    w2pk = (v4i*)carve((size_t)CMID * 16);
    float2* e2   = (float2*)carve((size_t)CMID * 8);
    int8_t* w3qp = (int8_t*)carve((size_t)COUT * 592);
    float2* e3   = (float2*)carve((size_t)COUT * 8);
    u32*    x8t2 = (u32*)carve((size_t)B_ * XB4 * 16);   // 6.8 MB
    (void)ws_size; (void)in_sizes; (void)n_in; (void)out_size;

    prep_all<<<dim3(760), dim3(256), 0, stream>>>(
        x, w1, g1, b1, m1, v1, w2, g2, b2, m2, v2, w3, g3, b3, m3, v3,
        r0, r1, r2, cl, x8t2,
        w1qp, e1, w2pk, e2, w3qp, e3);

    conv123c<<<dim3(14, B_), dim3(256), 0, stream>>>(
        (const v4i*)x8t2, (const v4i*)w1qp, e1, w2pk, e2, w3qp, e3,
        x, r1, r2, r3, cl, out);
}

// Round 14
// 163.556 us; speedup vs baseline: 1.0357x; 1.0041x over previous
//
#include <hip/hip_runtime.h>
#include <cstdint>
#include <cstddef>

typedef int   v4i __attribute__((ext_vector_type(4)));
typedef float v4f __attribute__((ext_vector_type(4)));
typedef unsigned int u32;

constexpr int B_   = 64;
constexpr int CIN  = 96;
constexpr int P_   = 784;     // 28*28
constexpr int CMID = 576;
constexpr int COUT = 96;
constexpr int NOUT = B_ * COUT * P_;
constexpr float NBITF = 127.0f;
constexpr float EPSF  = 1e-5f;
constexpr float MAGICF = 12582912.0f;    // 1.5 * 2^23
constexpr int   BIASI  = 0x4B400000;     // float bits of MAGICF (low byte 0)

// x8t2: v4i X[b][pt 13][g 8][pxl 64] = k-bytes 16g..16g+15 of px pt*64+pxl
//   (g 0..5 = ic 0..95, g 6..7 = zero K-pad 96->128). One MFMA A-frag = 1 v4i.
constexpr int XB4 = 13 * 8 * 64;        // v4i per batch (6656)
constexpr int Y1S = 28;                 // y1 scratch stride (dw/ch) — no pad:
                                        // block LDS 53760 B = 105 x 512-B
                                        // granules -> 3 blocks/CU.

__device__ __forceinline__ int dot3(u32 a, u32 w, int acc) {
#if __has_builtin(__builtin_amdgcn_sdot4)
    return __builtin_amdgcn_sdot4((int)a, (int)w, acc, false);
#else
    return acc + (int)(signed char)(a)        * (int)(signed char)(w)
               + (int)(signed char)(a >> 8)   * (int)(signed char)(w >> 8)
               + (int)(signed char)(a >> 16)  * (int)(signed char)(w >> 16);
#endif
}

__device__ __forceinline__ void tr4(u32 S0, u32 S1, u32 S2, u32 S3, u32 O[4]) {
    u32 u01 = __builtin_amdgcn_perm(S1, S0, 0x05010400u);
    u32 u23 = __builtin_amdgcn_perm(S3, S2, 0x05010400u);
    u32 v01 = __builtin_amdgcn_perm(S1, S0, 0x07030602u);
    u32 v23 = __builtin_amdgcn_perm(S3, S2, 0x07030602u);
    O[0] = __builtin_amdgcn_perm(u23, u01, 0x05040100u);
    O[1] = __builtin_amdgcn_perm(u23, u01, 0x07060302u);
    O[2] = __builtin_amdgcn_perm(v23, v01, 0x05040100u);
    O[3] = __builtin_amdgcn_perm(v23, v01, 0x07060302u);
}

__device__ __forceinline__ u32 pack4(u32 t0, u32 t1, u32 t2, u32 t3) {
    u32 p01 = __builtin_amdgcn_perm(t1, t0, 0x05010400u);
    u32 p23 = __builtin_amdgcn_perm(t3, t2, 0x05010400u);
    return __builtin_amdgcn_perm(p23, p01, 0x05040100u);
}

// ---------------------------------------------------------------------------
// prep_all: blocks [0,448) = quant_x into x8t2; blocks [448,760) = weight
// prep (4 single-wave jobs/block) emitting int8 levels + folded epilogue
// constants e1/e2/e3 = {scale, bias} per channel.
// ---------------------------------------------------------------------------
__global__ __launch_bounds__(256)
void prep_all(const float* __restrict__ x,
              const float* __restrict__ w1, const float* __restrict__ g1,
              const float* __restrict__ b1, const float* __restrict__ m1,
              const float* __restrict__ v1,
              const float* __restrict__ w2, const float* __restrict__ g2,
              const float* __restrict__ b2, const float* __restrict__ m2,
              const float* __restrict__ v2,
              const float* __restrict__ w3, const float* __restrict__ g3,
              const float* __restrict__ b3, const float* __restrict__ m3,
              const float* __restrict__ v3,
              const float* __restrict__ r0, const float* __restrict__ r1,
              const float* __restrict__ r2, const int* __restrict__ cluster,
              u32* __restrict__ x8t2,
              int8_t* __restrict__ w1qp, float2* __restrict__ e1,
              v4i* __restrict__ w2pk,    float2* __restrict__ e2,
              int8_t* __restrict__ w3qp, float2* __restrict__ e3)
{
    __shared__ u32 T[112 * 37];
    int tid = threadIdx.x;
    int c = cluster[0];

    if (blockIdx.x < 448) {
        int pt0 = blockIdx.x % 7, b = blockIdx.x / 7;
        float inv_s0 = NBITF / r0[c];

        for (int i = tid; i < 112 * 8; i += 256) {      // zero kdw 24..31
            int row = i >> 3, cc = 24 + (i & 7);
            T[row * 37 + cc] = 0u;
        }
        for (int u = tid; u < 24 * 28; u += 256) {
            int pq = u % 28, icq = u / 28;
            int pxb = pt0 * 112 + pq * 4;
            int q[4][4];
            #pragma unroll
            for (int j = 0; j < 4; j++) {
                v4f xv = *(const v4f*)(x + ((size_t)b * CIN + icq * 4 + j) * P_ + pxb);
                #pragma unroll
                for (int i = 0; i < 4; i++)
                    q[j][i] = (int)fminf(fmaxf(rintf(xv[i] * inv_s0), -127.f), 127.f);
            }
            #pragma unroll
            for (int i = 0; i < 4; i++) {
                u32 t0 = __builtin_amdgcn_perm((u32)q[1][i], (u32)q[0][i], 0x00000400u);
                u32 t1 = __builtin_amdgcn_perm((u32)q[3][i], (u32)q[2][i], 0x00000400u);
                T[(pq * 4 + i) * 37 + icq] = __builtin_amdgcn_perm(t1, t0, 0x05040100u);
            }
        }
        __syncthreads();
        u32* gb = x8t2 + (size_t)b * XB4 * 4;
        for (int i = tid; i < 32 * 112; i += 256) {
            int icq = i / 112, pxo = i - icq * 112;
            int px = pt0 * 112 + pxo;
            gb[(((px >> 6) * 8 + (icq >> 2)) * 64 + (px & 63)) * 4 + (icq & 3)] =
                T[pxo * 37 + icq];
        }
        return;
    }

    int lane = tid & 63, wv = tid >> 6;
    int blk = (blockIdx.x - 448) * 4 + wv;   // 0..1247

    const float *w, *g, *bb, *mm, *vv;
    int oc, K, which;
    if (blk < CMID)            { which = 0; w = w1; g = g1; bb = b1; mm = m1; vv = v1; oc = blk;            K = CIN;  }
    else if (blk < 2 * CMID)   { which = 1; w = w2; g = g2; bb = b2; mm = m2; vv = v2; oc = blk - CMID;     K = 9;    }
    else                       { which = 2; w = w3; g = g3; bb = b3; mm = m3; vv = v3; oc = blk - 2 * CMID; K = CMID; }

    float scale = g[oc] / sqrtf(vv[oc] + EPSF);

    float mx = 0.f;
    for (int k = lane; k < K; k += 64)
        mx = fmaxf(mx, fabsf(w[oc * K + k] * scale));
    #pragma unroll
    for (int off = 1; off < 64; off <<= 1)
        mx = fmaxf(mx, __shfl_xor(mx, off));

    float s = mx / NBITF;

    int myq = 0;
    for (int k = lane; k < K; k += 64) {
        float wf = w[oc * K + k] * scale;
        float q  = fminf(fmaxf(rintf(wf / s), -127.f), 127.f);
        if (which == 0)      w1qp[oc * 144 + k] = (int8_t)q;
        else if (which == 1) myq = (int)q;
        else                 w3qp[oc * 592 + k] = (int8_t)q;
    }
    if (which == 0 && lane < 12)
        ((u32*)(w1qp + oc * 144))[24 + lane] = 0u;
    if (which == 1) {
        u32 qq[9];
        #pragma unroll
        for (int t = 0; t < 9; t++) qq[t] = (u32)__shfl(myq, t, 64) & 0xffu;
        if (lane == 0) {
            v4i pk;
            pk[0] = (int)(qq[0] | (qq[1] << 8) | (qq[2] << 16));
            pk[1] = (int)(qq[3] | (qq[4] << 8) | (qq[5] << 16));
            pk[2] = (int)(qq[6] | (qq[7] << 8) | (qq[8] << 16));
            pk[3] = 0;
            w2pk[oc] = pk;
        }
    }
    if (lane == 0) {
        float bf = bb[oc] - mm[oc] * scale;
        float s0 = r0[c] / NBITF, s1 = r1[c] / NBITF, s2 = r2[c] / NBITF;
        if (which == 0) {
            float inv_s1 = NBITF / r1[c];
            e1[oc] = make_float2(s0 * s * inv_s1, bf * inv_s1);
        } else if (which == 1) {
            float inv_s2 = NBITF / r2[c];
            e2[oc] = make_float2(s1 * s * inv_s2, bf * inv_s2);
        } else {
            e3[oc] = make_float2(s2 * s, bf);
        }
    }
}

// ---------------------------------------------------------------------------
// conv123d: fully fused conv1 + depthwise + conv3 (R13 structure) with LDS
// trimmed under the 3-blocks/CU threshold: y1 scratch stride 29 -> 28 dw/ch
// (53760 B total = 105 x 512-B granules; 3 x 53760 <= 160 KB). Depthwise
// writes y2 in-place over y1 rows 0/3. One block barrier; conv3 MFMA +
// residual + requant. Grid (14 rt, 64 b).
// ---------------------------------------------------------------------------
__global__ __launch_bounds__(256)
void conv123d(const v4i* __restrict__ x8t2, const v4i* __restrict__ w1q4,
              const float2* __restrict__ e1,
              const v4i* __restrict__ w2pk, const float2* __restrict__ e2,
              const int8_t* __restrict__ w3qp, const float2* __restrict__ e3,
              const float* __restrict__ x,
              const float* __restrict__ r1, const float* __restrict__ r2,
              const float* __restrict__ r3, const int* __restrict__ cluster,
              float* __restrict__ out)
{
    __shared__ u32 y1s[4][48 * Y1S];    // per-wave scratch   21504 B
    __shared__ v4i y2c[36 * 56];        // shared ch-packed   32256 B

    int tid = threadIdx.x, b = blockIdx.y, rt = blockIdx.x;
    int R0 = 2 * rt;
    int W0 = (R0 - 1) * 28;             // window px base (may be -28)
    int lane = tid & 63, wv = tid >> 6;
    int n = lane & 15, q4 = lane >> 4;

    int   c      = cluster[0];
    int   u1i    = (int)fminf(rintf(6.f * NBITF / r1[c]), 127.f);
    int   u2i    = (int)fminf(rintf(6.f * NBITF / r2[c]), 127.f);
    float s3     = r3[c] / NBITF;
    float inv_s3 = NBITF / r3[c];

    // window A-frag base offsets (reused across chunks; L1-resident)
    const v4i* xb = x8t2 + (size_t)b * XB4;
    int pb[7];
    #pragma unroll
    for (int jm = 0; jm < 7; jm++) {
        int px = min(max(W0 + 16 * jm + n, 0), P_ - 1);
        pb[jm] = (px >> 6) * 512 + (px & 63);
    }

    u32* myY1 = y1s[wv];

    for (int ck = 0; ck < 3; ck++) {
        int oc0 = wv * 144 + ck * 48;

        // ---- conv1: 48 oc, jm-outer with jn inner, fused epilogue ----
        v4i    bw[3][2];
        float2 ee[3];
        #pragma unroll
        for (int jn = 0; jn < 3; jn++) {
            int oc = oc0 + 16 * jn + n;
            bw[jn][0] = w1q4[oc * 9 + q4];
            bw[jn][1] = w1q4[oc * 9 + 4 + q4];
            ee[jn] = e1[oc];
        }
        #pragma unroll
        for (int jm = 0; jm < 7; jm++) {
            v4i af0 = xb[pb[jm] + q4 * 64];
            v4i af1 = xb[pb[jm] + (4 + q4) * 64];
            int dw = 4 * jm + q4;                       // 0..27
            bool valid = (unsigned)(W0 + 4 * dw) < (unsigned)P_;

            #pragma unroll
            for (int jn = 0; jn < 3; jn++) {
                v4i acc = (v4i){0, 0, 0, 0};
                acc = __builtin_amdgcn_mfma_i32_16x16x64_i8(af0, bw[jn][0], acc, 0, 0, 0);
                acc = __builtin_amdgcn_mfma_i32_16x16x64_i8(af1, bw[jn][1], acc, 0, 0, 0);
                u32 t[4];
                #pragma unroll
                for (int r = 0; r < 4; r++) {
                    float f = fmaf((float)acc[r], ee[jn].x, ee[jn].y) + MAGICF;
                    t[r] = (u32)min(max(__float_as_int(f), BIASI), BIASI + u1i);
                }
                u32 pk = pack4(t[0], t[1], t[2], t[3]);
                myY1[(16 * jn + n) * Y1S + dw] = valid ? pk : 0u;
            }
        }

        // ---- depthwise 3x3: 48 ch x 2 rows = 96 units over 64 lanes.
        //      y2 written IN-PLACE: orow0 -> y1 row0 slot, orow1 -> row3.
        for (int u = lane; u < 96; u += 64) {
            int chl = u >> 1, orow = u & 1;
            int ch  = oc0 + chl;
            int rb  = chl * Y1S + orow * 7;             // first read row
            int wb  = chl * Y1S + orow * 21;            // write row (0 or 3)

            v4i wpk = w2pk[ch];
            u32 pk0 = (u32)wpk[0], pk1 = (u32)wpk[1], pk2 = (u32)wpk[2];
            float2 e = e2[ch];

            u32 M0 = 0, M1 = 0, M2 = 0;
            u32 D0 = myY1[rb], D1 = myY1[rb + 7], D2 = myY1[rb + 14];
            #pragma unroll
            for (int xq = 0; xq < 7; xq++) {
                u32 N0, N1, N2;
                if (xq < 6) {
                    N0 = myY1[rb + xq + 1];
                    N1 = myY1[rb + 7 + xq + 1];
                    N2 = myY1[rb + 14 + xq + 1];
                } else { N0 = N1 = N2 = 0u; }

                int a0, a1, a2, a3;
                a0 = dot3(__builtin_amdgcn_alignbyte(D0, M0, 3), pk0, 0);
                a0 = dot3(__builtin_amdgcn_alignbyte(D1, M1, 3), pk1, a0);
                a0 = dot3(__builtin_amdgcn_alignbyte(D2, M2, 3), pk2, a0);
                a1 = dot3(D0, pk0, 0);
                a1 = dot3(D1, pk1, a1);
                a1 = dot3(D2, pk2, a1);
                a2 = dot3(__builtin_amdgcn_alignbyte(N0, D0, 1), pk0, 0);
                a2 = dot3(__builtin_amdgcn_alignbyte(N1, D1, 1), pk1, a2);
                a2 = dot3(__builtin_amdgcn_alignbyte(N2, D2, 1), pk2, a2);
                a3 = dot3(__builtin_amdgcn_alignbyte(N0, D0, 2), pk0, 0);
                a3 = dot3(__builtin_amdgcn_alignbyte(N1, D1, 2), pk1, a3);
                a3 = dot3(__builtin_amdgcn_alignbyte(N2, D2, 2), pk2, a3);

                int aa[4] = {a0, a1, a2, a3};
                u32 tq[4];
                #pragma unroll
                for (int i = 0; i < 4; i++) {
                    float f = fmaf((float)aa[i], e.x, e.y) + MAGICF;
                    tq[i] = (u32)min(max(__float_as_int(f), BIASI), BIASI + u2i);
                }
                myY1[wb + xq] = pack4(tq[0], tq[1], tq[2], tq[3]);

                M0 = D0; M1 = D1; M2 = D2;
                D0 = N0; D1 = N1; D2 = N2;
            }
        }

        // ---- tr4 -> shared ch-packed y2c (42 units, lanes 0..41) ----
        if (lane < 42) {
            int kgl = lane / 14, d = lane - kgl * 14;   // kgl 0..2, d 0..13
            int off = d + ((d >= 7) ? 14 : 0);          // y2 slot within ch
            u32 O[4][4];
            #pragma unroll
            for (int j = 0; j < 4; j++) {
                int ch0 = 16 * kgl + 4 * j;
                tr4(myY1[(ch0 + 0) * Y1S + off], myY1[(ch0 + 1) * Y1S + off],
                    myY1[(ch0 + 2) * Y1S + off], myY1[(ch0 + 3) * Y1S + off], O[j]);
            }
            int kgG = wv * 9 + ck * 3 + kgl;            // 0..35
            #pragma unroll
            for (int i = 0; i < 4; i++)
                y2c[kgG * 56 + 4 * d + i] =
                    (v4i){(int)O[0][i], (int)O[1][i], (int)O[2][i], (int)O[3][i]};
        }
    }
    __syncthreads();   // y2c complete

    // ---- conv3 MFMA + residual + requant ----
    int pxl = wv * 16 + n;               // 0..63, valid < 56
    int pxc = min(pxl, 55);
    const v4i* w34 = (const v4i*)w3qp;   // 37 v4i per oc row

    v4i acc3[6];
    #pragma unroll
    for (int i = 0; i < 6; i++) acc3[i] = (v4i){0, 0, 0, 0};

    #pragma unroll
    for (int ks = 0; ks < 9; ks++) {
        v4i bfr = y2c[(4 * ks + q4) * 56 + pxc];
        #pragma unroll
        for (int i = 0; i < 6; i++) {
            v4i afr = w34[(i * 16 + n) * 37 + 4 * ks + q4];
            acc3[i] = __builtin_amdgcn_mfma_i32_16x16x64_i8(afr, bfr, acc3[i], 0, 0, 0);
        }
    }

    if (pxl < 56) {
        int px = R0 * 28 + pxl;
        #pragma unroll
        for (int i = 0; i < 6; i++) {
            #pragma unroll
            for (int r = 0; r < 4; r++) {
                int    oc = i * 16 + q4 * 4 + r;
                float2 e  = e3[oc];
                size_t gi = (size_t)(b * COUT + oc) * P_ + px;
                float v  = fmaf((float)acc3[i][r], e.x, e.y) + x[gi];
                float f  = fmaf(v, inv_s3, MAGICF);
                int lvl  = min(max(__float_as_int(f) - BIASI, -127), 127);
                out[gi]  = (float)lvl * s3;
            }
        }
    }
    if (rt == 0 && b == 0 && tid == 0)
        out[NOUT] = s3;
}

// ---------------------------------------------------------------------------
extern "C" void kernel_launch(void* const* d_in, const int* in_sizes, int n_in,
                              void* d_out, int out_size, void* d_ws, size_t ws_size,
                              hipStream_t stream)
{
    const float* x  = (const float*)d_in[0];
    const float* w1 = (const float*)d_in[1];
    const float* g1 = (const float*)d_in[2];
    const float* b1 = (const float*)d_in[3];
    const float* m1 = (const float*)d_in[4];
    const float* v1 = (const float*)d_in[5];
    const float* w2 = (const float*)d_in[6];
    const float* g2 = (const float*)d_in[7];
    const float* b2 = (const float*)d_in[8];
    const float* m2 = (const float*)d_in[9];
    const float* v2 = (const float*)d_in[10];
    const float* w3 = (const float*)d_in[11];
    const float* g3 = (const float*)d_in[12];
    const float* b3 = (const float*)d_in[13];
    const float* m3 = (const float*)d_in[14];
    const float* v3 = (const float*)d_in[15];
    const float* r0 = (const float*)d_in[16];
    const float* r1 = (const float*)d_in[17];
    const float* r2 = (const float*)d_in[18];
    const float* r3 = (const float*)d_in[19];
    const int*   cl = (const int*)d_in[20];

    float* out = (float*)d_out;

    char*  ws  = (char*)d_ws;
    size_t off = 0;
    auto carve = [&](size_t bytes) {
        size_t cur = off;
        off = (off + bytes + 255) & ~(size_t)255;
        return (void*)(ws + cur);
    };
    int8_t* w1qp = (int8_t*)carve((size_t)CMID * 144);
    float2* e1   = (float2*)carve((size_t)CMID * 8);
    v4i*    w2pk = (v4i*)carve((size_t)CMID * 16);
    float2* e2   = (float2*)carve((size_t)CMID * 8);
    int8_t* w3qp = (int8_t*)carve((size_t)COUT * 592);
    float2* e3   = (float2*)carve((size_t)COUT * 8);
    u32*    x8t2 = (u32*)carve((size_t)B_ * XB4 * 16);   // 6.8 MB
    (void)ws_size; (void)in_sizes; (void)n_in; (void)out_size;

    prep_all<<<dim3(760), dim3(256), 0, stream>>>(
        x, w1, g1, b1, m1, v1, w2, g2, b2, m2, v2, w3, g3, b3, m3, v3,
        r0, r1, r2, cl, x8t2,
        w1qp, e1, w2pk, e2, w3qp, e3);

    conv123d<<<dim3(14, B_), dim3(256), 0, stream>>>(
        (const v4i*)x8t2, (const v4i*)w1qp, e1, w2pk, e2, w3qp, e3,
        x, r1, r2, r3, cl, out);
}